// Round 1
// baseline (200.767 us; speedup 1.0000x reference)
//
#include <hip/hip_runtime.h>

#define NB 16
#define NC 7
#define NK 6
#define HC 160
#define WC 160
#define HF 640
#define WF 640
#define NCOARSE (HC*WC)          // 25600 coarse pixels per batch
#define NFINE   (HF*WF)          // 409600 fine pixels per batch
#define NCB     (NB*NCOARSE)     // 409600 total coarse pixels
#define BLOCKS_PER_B (NCOARSE/256)  // 100
#define NACC 27
#define ACC_STRIDE 32
#define EPSF 1e-6f

// ws layout (bytes):
//   acc      float[16*32]   @ 0       (8192)
//   pos_num  int[16]        @ 8192
//   neg_tot  int[16]        @ 8256
//   thr      float[16]      @ 8320
//   fallback int[16]        @ 8384
//   keys     uint[409600]   @ 16384   (1638400)
//   wneg     uchar[409600]  @ 16384+1638400
#define WS_POS  8192
#define WS_NEG  8256
#define WS_THR  8320
#define WS_FLB  8384
#define WS_KEYS 16384
#define WS_WNEG (16384 + NCB*4)

// ---------- Phase A: per-coarse-pixel neg weights + keys, per-batch pos/neg counts ----------
__global__ __launch_bounds__(256) void psel_phaseA(
    const float* __restrict__ maps, const float* __restrict__ gt,
    const float* __restrict__ tm, int* __restrict__ pos_num,
    int* __restrict__ neg_tot, unsigned* __restrict__ keys,
    unsigned char* __restrict__ wneg)
{
    int bid = blockIdx.x;
    int b = bid / BLOCKS_PER_B;
    int r = (bid % BLOCKS_PER_B) * 256 + threadIdx.x;   // coarse index in batch
    int cy = r / WC, cx = r % WC;
    const float* gtb = gt + (size_t)b * NFINE;
    const float* tmb = tm + (size_t)b * NFINE;
    float fpos = 0.f, gsum = 0.f;
    #pragma unroll
    for (int row = 0; row < 4; ++row) {
        int off = (cy*4 + row)*WF + cx*4;
        float4 g4 = *reinterpret_cast<const float4*>(gtb + off);
        float4 m4 = *reinterpret_cast<const float4*>(tmb + off);
        gsum += g4.x + g4.y + g4.z + g4.w;
        fpos += g4.x*m4.x + g4.y*m4.y + g4.z*m4.z + g4.w*m4.w;
    }
    int posc = (int)fpos;          // exact: sums of 0/1
    int negc = 16 - (int)gsum;     // # fine pixels with g==0
    // order-preserving key of the (coarse) score
    float s = maps[(size_t)b * NC * NCOARSE + r];   // channel 0
    unsigned u = __float_as_uint(s);
    unsigned key = (u & 0x80000000u) ? ~u : (u | 0x80000000u);
    keys[b*NCOARSE + r] = key;
    wneg[b*NCOARSE + r] = (unsigned char)negc;
    // block-reduce pos/neg counts
    #pragma unroll
    for (int off = 32; off; off >>= 1) {
        posc += __shfl_down(posc, off);
        negc += __shfl_down(negc, off);
    }
    __shared__ int sp[4], sn[4];
    int wid = threadIdx.x >> 6, lane = threadIdx.x & 63;
    if (lane == 0) { sp[wid] = posc; sn[wid] = negc; }
    __syncthreads();
    if (threadIdx.x == 0) {
        atomicAdd(&pos_num[b], sp[0]+sp[1]+sp[2]+sp[3]);
        atomicAdd(&neg_tot[b], sn[0]+sn[1]+sn[2]+sn[3]);
    }
}

// ---------- Phase B: weighted radix-select of the OHEM threshold, 1 block per batch ----------
__global__ __launch_bounds__(256) void psel_phaseB(
    const unsigned* __restrict__ keys, const unsigned char* __restrict__ wneg,
    const int* __restrict__ pos_num, const int* __restrict__ neg_tot,
    float* __restrict__ thr, int* __restrict__ fallback)
{
    int b = blockIdx.x;
    long long pos = pos_num[b];
    long long negT = neg_tot[b];
    long long neg_num = pos * 3; if (neg_num > negT) neg_num = negT;
    if (pos == 0 || neg_num == 0) {
        if (threadIdx.x == 0) { fallback[b] = 1; thr[b] = -3.0e38f; }
        return;
    }
    __shared__ int hist[256];
    __shared__ unsigned sh_prefix;
    __shared__ int sh_k;
    if (threadIdx.x == 0) { sh_prefix = 0u; sh_k = (int)neg_num; }
    const unsigned* kb = keys + b*NCOARSE;
    const unsigned char* wb = wneg + b*NCOARSE;
    for (int bp = 3; bp >= 0; --bp) {
        __syncthreads();
        hist[threadIdx.x] = 0;
        __syncthreads();
        unsigned prefix = sh_prefix;
        int k = sh_k;
        for (int i = threadIdx.x; i < NCOARSE; i += 256) {
            unsigned key = kb[i];
            bool match = (bp == 3) || ((key >> ((bp+1)*8)) == prefix);
            if (match) {
                int w = wb[i];
                if (w) atomicAdd(&hist[(key >> (bp*8)) & 255], w);
            }
        }
        __syncthreads();
        if (threadIdx.x == 0) {
            int cum = 0, v;
            for (v = 255; v >= 0; --v) {
                cum += hist[v];
                if (cum >= k) break;
            }
            if (v < 0) v = 0;
            sh_k = k - (cum - hist[v]);
            sh_prefix = (prefix << 8) | (unsigned)v;
        }
    }
    __syncthreads();
    if (threadIdx.x == 0) {
        unsigned key = sh_prefix;
        unsigned u = (key & 0x80000000u) ? (key & 0x7fffffffu) : ~key;
        thr[b] = __uint_as_float(u);
        fallback[b] = 0;
    }
}

// ---------- Phase C: main fused reduction into 27 per-batch sums ----------
__global__ __launch_bounds__(256) void psel_phaseC(
    const float* __restrict__ maps, const float* __restrict__ gt,
    const float* __restrict__ gk, const float* __restrict__ tm,
    const float* __restrict__ thr, const int* __restrict__ fallback,
    float* __restrict__ acc)
{
    int bid = blockIdx.x;
    int b = bid / BLOCKS_PER_B;
    int r = (bid % BLOCKS_PER_B) * 256 + threadIdx.x;
    int cy = r / WC, cx = r % WC;

    float sig[NC]; float mv0, mv6;
    {
        float m0 = 0.f;
        #pragma unroll
        for (int c = 0; c < NC; ++c) {
            float mv = maps[((size_t)(b*NC + c))*NCOARSE + r];
            if (c == 0) mv0 = mv;
            if (c == 6) mv6 = mv;
            sig[c] = 1.0f / (1.0f + expf(-mv));
            (void)m0;
        }
    }
    bool at = mv0 > 0.0f;
    bool a5 = mv6 > 0.0f;
    bool cthr = (fallback[b] != 0) || (mv0 >= thr[b]);

    float cm = 0.f, cgm = 0.f, cg5mg = 0.f;
    float cgkm[NK] = {0.f,0.f,0.f,0.f,0.f,0.f};
    const float* gtb = gt + (size_t)b * NFINE;
    const float* tmb = tm + (size_t)b * NFINE;
    #pragma unroll
    for (int row = 0; row < 4; ++row) {
        int off = (cy*4 + row)*WF + cx*4;
        float4 g4 = *reinterpret_cast<const float4*>(gtb + off);
        float4 m4 = *reinterpret_cast<const float4*>(tmb + off);
        cm  += m4.x + m4.y + m4.z + m4.w;
        float gmx = g4.x*m4.x, gmy = g4.y*m4.y, gmz = g4.z*m4.z, gmw = g4.w*m4.w;
        cgm += gmx + gmy + gmz + gmw;
        #pragma unroll
        for (int k = 0; k < NK; ++k) {
            const float* gkb = gk + ((size_t)(b*NK + k)*HF + (cy*4 + row))*WF + cx*4;
            float4 k4 = *reinterpret_cast<const float4*>(gkb);
            cgkm[k] += k4.x*m4.x + k4.y*m4.y + k4.z*m4.z + k4.w*m4.w;
            if (k == NK-1)
                cg5mg += k4.x*gmx + k4.y*gmy + k4.z*gmz + k4.w*gmw;
        }
    }

    float vals[NACC];
    float s0 = sig[0];
    vals[0] = s0 * cgm;                          // A_t = sum sig*g*sel
    vals[1] = s0 * s0 * (cthr ? cm : cgm);       // B_t = sum sig^2*sel
    vals[2] = cgm;                               // C_t = S_cgm (= valid2)
    vals[3] = cm;                                // S_cm
    vals[4] = at ? cgm : 0.f;                    // S_at_cgm  (n11 text)
    vals[5] = at ? cm  : 0.f;                    // S_at_cm
    #pragma unroll
    for (int k = 0; k < NK; ++k) {
        float sk = sig[k+1];
        vals[6 + 3*k] = at ? sk * cgkm[k] : 0.f;       // A_k
        vals[7 + 3*k] = at ? sk * sk * cm : 0.f;       // B_k
        vals[8 + 3*k] = at ? cgkm[k] : 0.f;            // C_k
    }
    vals[24] = a5 ? cg5mg : 0.f;                 // m11 kernel-iou
    vals[25] = a5 ? cgm   : 0.f;                 // S_a5_cgm
    vals[26] = cg5mg;                            // S_cg5mg

    #pragma unroll
    for (int i = 0; i < NACC; ++i) {
        #pragma unroll
        for (int off = 32; off; off >>= 1)
            vals[i] += __shfl_down(vals[i], off);
    }
    __shared__ float red[4][NACC];
    int wid = threadIdx.x >> 6, lane = threadIdx.x & 63;
    if (lane == 0) {
        #pragma unroll
        for (int i = 0; i < NACC; ++i) red[wid][i] = vals[i];
    }
    __syncthreads();
    if (threadIdx.x < NACC) {
        float s = red[0][threadIdx.x] + red[1][threadIdx.x]
                + red[2][threadIdx.x] + red[3][threadIdx.x];
        atomicAdd(&acc[b*ACC_STRIDE + threadIdx.x], s);
    }
}

// ---------- Phase D: final per-batch algebra + output sums ----------
__global__ __launch_bounds__(64) void psel_phaseD(
    const float* __restrict__ acc, float* __restrict__ out)
{
    int b = threadIdx.x;
    float l = 0.f, lt = 0.f, lk = 0.f, it = 0.f, ik = 0.f;
    if (b < NB) {
        const float* a = acc + b*ACC_STRIDE;
        float At = a[0], Bt = a[1], Ct = a[2], Sm = a[3], Satgm = a[4], Satm = a[5];
        lt = 1.f - 2.f*At / (Bt + Ct + 2.f*EPSF);
        // text IoU
        float n11 = Satgm;
        float u1 = Satm + Ct - Satgm;    // union class 1
        float i0 = Sm - u1;              // inter class 0
        float u0 = Sm - n11;             // union class 0
        it = 0.5f * (i0/(u0 + EPSF) + n11/(u1 + EPSF));
        // kernel dice (mean over K)
        float lks = 0.f;
        #pragma unroll
        for (int k = 0; k < NK; ++k) {
            float Ak = a[6+3*k], Bk = a[7+3*k], Ck = a[8+3*k];
            lks += 1.f - 2.f*Ak / (Bk + Ck + 2.f*EPSF);
        }
        lk = lks / (float)NK;
        // kernel IoU (valid = g*m, count = Ct)
        float m11 = a[24], Sa5gm = a[25], Sg5 = a[26];
        float ku1 = Sa5gm + Sg5 - m11;
        float ki0 = Ct - ku1;
        float ku0 = Ct - m11;
        ik = 0.5f * (ki0/(ku0 + EPSF) + m11/(ku1 + EPSF));
        l = 0.7f*lt + 0.3f*lk;
    }
    #pragma unroll
    for (int off = 8; off; off >>= 1) {
        l  += __shfl_down(l,  off);
        lt += __shfl_down(lt, off);
        lk += __shfl_down(lk, off);
        it += __shfl_down(it, off);
        ik += __shfl_down(ik, off);
    }
    if (threadIdx.x == 0) {
        out[0] = l; out[1] = lt; out[2] = lk; out[3] = it; out[4] = ik;
    }
}

extern "C" void kernel_launch(void* const* d_in, const int* in_sizes, int n_in,
                              void* d_out, int out_size, void* d_ws, size_t ws_size,
                              hipStream_t stream) {
    const float* maps = (const float*)d_in[0];
    const float* gt   = (const float*)d_in[1];
    const float* gk   = (const float*)d_in[2];
    const float* tm   = (const float*)d_in[3];
    float* out = (float*)d_out;
    char* ws = (char*)d_ws;
    float* acc          = (float*)ws;
    int*   pos_num      = (int*)(ws + WS_POS);
    int*   neg_tot      = (int*)(ws + WS_NEG);
    float* thr          = (float*)(ws + WS_THR);
    int*   fallback     = (int*)(ws + WS_FLB);
    unsigned* keys      = (unsigned*)(ws + WS_KEYS);
    unsigned char* wneg = (unsigned char*)(ws + WS_WNEG);

    hipMemsetAsync(ws, 0, 8448, stream);   // zero acc + pos/neg counters
    psel_phaseA<<<NB*BLOCKS_PER_B, 256, 0, stream>>>(maps, gt, tm, pos_num, neg_tot, keys, wneg);
    psel_phaseB<<<NB, 256, 0, stream>>>(keys, wneg, pos_num, neg_tot, thr, fallback);
    psel_phaseC<<<NB*BLOCKS_PER_B, 256, 0, stream>>>(maps, gt, gk, tm, thr, fallback, acc);
    psel_phaseD<<<1, 64, 0, stream>>>(acc, out);
}

// Round 2
// 123.685 us; speedup vs baseline: 1.6232x; 1.6232x over previous
//
#include <hip/hip_runtime.h>

#define NB 16
#define NC 7
#define NK 6
#define HC 160
#define WC 160
#define HF 640
#define WF 640
#define NCOARSE (HC*WC)             // 25600 coarse pixels per batch
#define NFINE   (HF*WF)             // 409600 fine pixels per batch
#define BLOCKS_PER_B (NCOARSE/256)  // 100
#define NACC 27
#define ACC_STRIDE 32
#define EPSF 1e-6f

// ---------------- ws layout (bytes) ----------------
// acc      float[16*32]        @ 0          (2048)
// pos_num  int[16]             @ 2048
// neg_tot  int[16]             @ 2112
// v1       int[16]             @ 2176
// k2       int[16]             @ 2240
// v2       int[16]             @ 2304
// k3       int[16]             @ 2368
// fallback int[16]             @ 2432
// hist1    int[16][2048]       @ 4096       (131072)
// hist2    int[16][2048]       @ 135168     (131072)
// hist3    int[16][1024]       @ 266240     (65536)
// bits     uint[16*25600]      @ 331776     (1638400)   [not zeroed]
#define WS_POS   2048
#define WS_NEG   2112
#define WS_V1    2176
#define WS_K2    2240
#define WS_V2    2304
#define WS_K3    2368
#define WS_FLB   2432
#define WS_H1    4096
#define WS_H2    135168
#define WS_H3    266240
#define WS_BITS  331776
#define WS_ZERO_BYTES 331776

__device__ __forceinline__ unsigned score_key(float s) {
    unsigned u = __float_as_uint(s);
    return (u & 0x80000000u) ? ~u : (u | 0x80000000u);
}

// Chunked weighted descending select: find bin v such that cumulative weight
// (from bin NBINS-1 downward) first reaches >= k at v; krem = k - weight strictly above v.
// All 256 threads must call (block-uniform). Result broadcast to all threads.
template<int NBINS>
__device__ __forceinline__ void select_bin(const int* __restrict__ gh, int k, int& bin, int& krem)
{
    constexpr int CH = NBINS / 256;
    __shared__ int lh[NBINS];
    __shared__ int cs[256];
    __shared__ int res[2];
    int t = threadIdx.x;
    #pragma unroll
    for (int i = 0; i < CH; ++i) lh[t + 256*i] = gh[t + 256*i];
    __syncthreads();
    int s = 0;
    #pragma unroll
    for (int j = 0; j < CH; ++j) s += lh[t*CH + j];
    cs[t] = s;
    __syncthreads();
    if (t == 0) {
        int cum = 0, v = 0; bool found = false;
        for (int c = 255; c >= 0 && !found; --c) {
            if (cum + cs[c] >= k) {
                for (int u = c*CH + CH - 1; u >= c*CH; --u) {
                    cum += lh[u];
                    if (cum >= k) { v = u; found = true; break; }
                }
                if (!found) { v = c*CH; found = true; }   // guard (unreachable)
            } else cum += cs[c];
        }
        if (!found) { v = 0; cum = k; }                   // guard (unreachable)
        res[0] = v; res[1] = k - (cum - lh[v]);
    }
    __syncthreads();
    bin = res[0]; krem = res[1];
}

// ---------- Phase A: bit-pack g/m, pos/neg counts, level-1 weighted histogram ----------
__global__ __launch_bounds__(256) void psel_phaseA(
    const float* __restrict__ maps, const float* __restrict__ gt,
    const float* __restrict__ tm, int* __restrict__ pos_num,
    int* __restrict__ neg_tot, int* __restrict__ hist1,
    unsigned* __restrict__ bitsbuf)
{
    __shared__ int lh[2048];
    __shared__ int sp[4], sn[4];
    int t = threadIdx.x;
    #pragma unroll
    for (int i = 0; i < 8; ++i) lh[t + 256*i] = 0;

    int bid = blockIdx.x;
    int b = bid / BLOCKS_PER_B;
    int r = (bid % BLOCKS_PER_B) * 256 + t;
    int cy = r / WC, cx = r % WC;
    const float* gtb = gt + (size_t)b * NFINE;
    const float* tmb = tm + (size_t)b * NFINE;
    unsigned gb = 0, mb = 0;
    #pragma unroll
    for (int row = 0; row < 4; ++row) {
        int off = (cy*4 + row)*WF + cx*4;
        float4 g4 = *reinterpret_cast<const float4*>(gtb + off);
        float4 m4 = *reinterpret_cast<const float4*>(tmb + off);
        unsigned sh = 4*row;
        gb |= ((g4.x > 0.5f) ? 1u : 0u) << (sh+0);
        gb |= ((g4.y > 0.5f) ? 1u : 0u) << (sh+1);
        gb |= ((g4.z > 0.5f) ? 1u : 0u) << (sh+2);
        gb |= ((g4.w > 0.5f) ? 1u : 0u) << (sh+3);
        mb |= ((m4.x > 0.5f) ? 1u : 0u) << (sh+0);
        mb |= ((m4.y > 0.5f) ? 1u : 0u) << (sh+1);
        mb |= ((m4.z > 0.5f) ? 1u : 0u) << (sh+2);
        mb |= ((m4.w > 0.5f) ? 1u : 0u) << (sh+3);
    }
    bitsbuf[b*NCOARSE + r] = (mb << 16) | gb;
    int posc = __popc(gb & mb);
    int negc = 16 - __popc(gb);

    unsigned key = score_key(maps[(size_t)b * NC * NCOARSE + r]);  // channel 0
    __syncthreads();
    if (negc) atomicAdd(&lh[key >> 21], negc);

    // block-reduce pos/neg counts (64-lane wave)
    #pragma unroll
    for (int off = 32; off; off >>= 1) {
        posc += __shfl_down(posc, off);
        negc += __shfl_down(negc, off);
    }
    int wid = t >> 6, lane = t & 63;
    if (lane == 0) { sp[wid] = posc; sn[wid] = negc; }
    __syncthreads();
    if (t == 0) {
        atomicAdd(&pos_num[b], sp[0]+sp[1]+sp[2]+sp[3]);
        atomicAdd(&neg_tot[b], sn[0]+sn[1]+sn[2]+sn[3]);
    }
    // flush level-1 histogram
    int* gh = hist1 + b*2048;
    #pragma unroll
    for (int i = 0; i < 8; ++i) {
        int v = lh[t + 256*i];
        if (v) atomicAdd(&gh[t + 256*i], v);
    }
}

// ---------- Phase B2: scan level-1 (redundant per block) + build level-2 histogram ----------
__global__ __launch_bounds__(256) void psel_phaseB2(
    const float* __restrict__ maps, const unsigned* __restrict__ bitsbuf,
    const int* __restrict__ pos_num, const int* __restrict__ neg_tot,
    const int* __restrict__ hist1, int* __restrict__ hist2,
    int* __restrict__ v1s, int* __restrict__ k2s, int* __restrict__ flb)
{
    int bid = blockIdx.x;
    int b = bid / BLOCKS_PER_B;
    bool desig = (bid % BLOCKS_PER_B) == 0;
    long long pos = pos_num[b];
    long long negT = neg_tot[b];
    long long neg_num = pos * 3; if (neg_num > negT) neg_num = negT;
    if (pos == 0 || neg_num == 0) {
        if (desig && threadIdx.x == 0) flb[b] = 1;
        return;
    }
    int v1, k2;
    select_bin<2048>(hist1 + b*2048, (int)neg_num, v1, k2);
    if (desig && threadIdx.x == 0) { v1s[b] = v1; k2s[b] = k2; }

    int r = (bid % BLOCKS_PER_B) * 256 + threadIdx.x;
    unsigned key = score_key(maps[(size_t)b * NC * NCOARSE + r]);
    if ((int)(key >> 21) == v1) {
        int w = 16 - __popc(bitsbuf[b*NCOARSE + r] & 0xFFFFu);
        if (w) atomicAdd(&hist2[b*2048 + (int)((key >> 10) & 2047u)], w);
    }
}

// ---------- Phase B4: scan level-2 (redundant) + build level-3 histogram ----------
__global__ __launch_bounds__(256) void psel_phaseB4(
    const float* __restrict__ maps, const unsigned* __restrict__ bitsbuf,
    const int* __restrict__ hist2, int* __restrict__ hist3,
    const int* __restrict__ v1s, const int* __restrict__ k2s,
    int* __restrict__ v2s, int* __restrict__ k3s, const int* __restrict__ flb)
{
    int bid = blockIdx.x;
    int b = bid / BLOCKS_PER_B;
    if (flb[b]) return;
    bool desig = (bid % BLOCKS_PER_B) == 0;
    int v1 = v1s[b], k2 = k2s[b];
    int v2, k3;
    select_bin<2048>(hist2 + b*2048, k2, v2, k3);
    if (desig && threadIdx.x == 0) { v2s[b] = v2; k3s[b] = k3; }

    int r = (bid % BLOCKS_PER_B) * 256 + threadIdx.x;
    unsigned key = score_key(maps[(size_t)b * NC * NCOARSE + r]);
    if ((int)(key >> 10) == ((v1 << 11) | v2)) {
        int w = 16 - __popc(bitsbuf[b*NCOARSE + r] & 0xFFFFu);
        if (w) atomicAdd(&hist3[b*1024 + (int)(key & 1023u)], w);
    }
}

// ---------- Phase C: scan level-3 (redundant) + main fused reduction ----------
__global__ __launch_bounds__(256) void psel_phaseC(
    const float* __restrict__ maps, const float* __restrict__ gk,
    const unsigned* __restrict__ bitsbuf, const int* __restrict__ hist3,
    const int* __restrict__ v1s, const int* __restrict__ v2s,
    const int* __restrict__ k3s, const int* __restrict__ flb,
    float* __restrict__ acc)
{
    int bid = blockIdx.x;
    int b = bid / BLOCKS_PER_B;
    int fb = flb[b];
    unsigned thrkey = 0;
    if (!fb) {
        int v3, ku;
        select_bin<1024>(hist3 + b*1024, k3s[b], v3, ku);
        thrkey = ((unsigned)v1s[b] << 21) | ((unsigned)v2s[b] << 10) | (unsigned)v3;
    }

    int r = (bid % BLOCKS_PER_B) * 256 + threadIdx.x;
    int cy = r / WC, cx = r % WC;

    float sig[NC]; float mv0 = 0.f, mv6 = 0.f;
    #pragma unroll
    for (int c = 0; c < NC; ++c) {
        float mv = maps[((size_t)(b*NC + c))*NCOARSE + r];
        if (c == 0) mv0 = mv;
        if (c == 6) mv6 = mv;
        sig[c] = 1.0f / (1.0f + expf(-mv));
    }
    bool at = mv0 > 0.0f;
    bool a5 = mv6 > 0.0f;
    bool cthr = fb || (score_key(mv0) >= thrkey);

    unsigned bits = bitsbuf[b*NCOARSE + r];
    unsigned mbits = bits >> 16, gbits = bits & 0xFFFFu;
    unsigned gmb = mbits & gbits;
    float cm  = (float)__popc(mbits);
    float cgm = (float)__popc(gmb);

    float cgkm[NK] = {0.f,0.f,0.f,0.f,0.f,0.f};
    float cg5mg = 0.f;
    #pragma unroll
    for (int row = 0; row < 4; ++row) {
        int fy = cy*4 + row;
        unsigned mrow = (mbits >> (4*row)) & 15u;
        unsigned grow = (gmb   >> (4*row)) & 15u;
        const float* base = gk + ((size_t)(b*NK)*HF + fy)*WF + cx*4;
        #pragma unroll
        for (int k = 0; k < NK; ++k) {
            float4 k4 = *reinterpret_cast<const float4*>(base + (size_t)k*HF*WF);
            float s = 0.f;
            if (mrow & 1u) s += k4.x;
            if (mrow & 2u) s += k4.y;
            if (mrow & 4u) s += k4.z;
            if (mrow & 8u) s += k4.w;
            cgkm[k] += s;
            if (k == NK-1) {
                float s5 = 0.f;
                if (grow & 1u) s5 += k4.x;
                if (grow & 2u) s5 += k4.y;
                if (grow & 4u) s5 += k4.z;
                if (grow & 8u) s5 += k4.w;
                cg5mg += s5;
            }
        }
    }

    float vals[NACC];
    float s0 = sig[0];
    vals[0] = s0 * cgm;                          // A_t
    vals[1] = s0 * s0 * (cthr ? cm : cgm);       // B_t
    vals[2] = cgm;                               // C_t
    vals[3] = cm;                                // S_cm
    vals[4] = at ? cgm : 0.f;                    // n11 text
    vals[5] = at ? cm  : 0.f;
    #pragma unroll
    for (int k = 0; k < NK; ++k) {
        float sk = sig[k+1];
        vals[6 + 3*k] = at ? sk * cgkm[k] : 0.f;       // A_k
        vals[7 + 3*k] = at ? sk * sk * cm : 0.f;       // B_k
        vals[8 + 3*k] = at ? cgkm[k] : 0.f;            // C_k
    }
    vals[24] = a5 ? cg5mg : 0.f;                 // m11 kernel-iou
    vals[25] = a5 ? cgm   : 0.f;
    vals[26] = cg5mg;

    #pragma unroll
    for (int i = 0; i < NACC; ++i) {
        #pragma unroll
        for (int off = 32; off; off >>= 1)
            vals[i] += __shfl_down(vals[i], off);
    }
    __shared__ float red[4][NACC];
    int wid = threadIdx.x >> 6, lane = threadIdx.x & 63;
    if (lane == 0) {
        #pragma unroll
        for (int i = 0; i < NACC; ++i) red[wid][i] = vals[i];
    }
    __syncthreads();
    if (threadIdx.x < NACC) {
        float s = red[0][threadIdx.x] + red[1][threadIdx.x]
                + red[2][threadIdx.x] + red[3][threadIdx.x];
        atomicAdd(&acc[b*ACC_STRIDE + threadIdx.x], s);
    }
}

// ---------- Phase D: final per-batch algebra + output sums ----------
__global__ __launch_bounds__(64) void psel_phaseD(
    const float* __restrict__ acc, float* __restrict__ out)
{
    int b = threadIdx.x;
    float l = 0.f, lt = 0.f, lk = 0.f, it = 0.f, ik = 0.f;
    if (b < NB) {
        const float* a = acc + b*ACC_STRIDE;
        float At = a[0], Bt = a[1], Ct = a[2], Sm = a[3], Satgm = a[4], Satm = a[5];
        lt = 1.f - 2.f*At / (Bt + Ct + 2.f*EPSF);
        float n11 = Satgm;
        float u1 = Satm + Ct - Satgm;
        float i0 = Sm - u1;
        float u0 = Sm - n11;
        it = 0.5f * (i0/(u0 + EPSF) + n11/(u1 + EPSF));
        float lks = 0.f;
        #pragma unroll
        for (int k = 0; k < NK; ++k) {
            float Ak = a[6+3*k], Bk = a[7+3*k], Ck = a[8+3*k];
            lks += 1.f - 2.f*Ak / (Bk + Ck + 2.f*EPSF);
        }
        lk = lks / (float)NK;
        float m11 = a[24], Sa5gm = a[25], Sg5 = a[26];
        float ku1 = Sa5gm + Sg5 - m11;
        float ki0 = Ct - ku1;
        float ku0 = Ct - m11;
        ik = 0.5f * (ki0/(ku0 + EPSF) + m11/(ku1 + EPSF));
        l = 0.7f*lt + 0.3f*lk;
    }
    #pragma unroll
    for (int off = 8; off; off >>= 1) {
        l  += __shfl_down(l,  off);
        lt += __shfl_down(lt, off);
        lk += __shfl_down(lk, off);
        it += __shfl_down(it, off);
        ik += __shfl_down(ik, off);
    }
    if (threadIdx.x == 0) {
        out[0] = l; out[1] = lt; out[2] = lk; out[3] = it; out[4] = ik;
    }
}

extern "C" void kernel_launch(void* const* d_in, const int* in_sizes, int n_in,
                              void* d_out, int out_size, void* d_ws, size_t ws_size,
                              hipStream_t stream) {
    const float* maps = (const float*)d_in[0];
    const float* gt   = (const float*)d_in[1];
    const float* gk   = (const float*)d_in[2];
    const float* tm   = (const float*)d_in[3];
    float* out = (float*)d_out;
    char* ws = (char*)d_ws;
    float* acc      = (float*)ws;
    int*   pos_num  = (int*)(ws + WS_POS);
    int*   neg_tot  = (int*)(ws + WS_NEG);
    int*   v1s      = (int*)(ws + WS_V1);
    int*   k2s      = (int*)(ws + WS_K2);
    int*   v2s      = (int*)(ws + WS_V2);
    int*   k3s      = (int*)(ws + WS_K3);
    int*   flb      = (int*)(ws + WS_FLB);
    int*   hist1    = (int*)(ws + WS_H1);
    int*   hist2    = (int*)(ws + WS_H2);
    int*   hist3    = (int*)(ws + WS_H3);
    unsigned* bits  = (unsigned*)(ws + WS_BITS);

    hipMemsetAsync(ws, 0, WS_ZERO_BYTES, stream);
    psel_phaseA <<<NB*BLOCKS_PER_B, 256, 0, stream>>>(maps, gt, tm, pos_num, neg_tot, hist1, bits);
    psel_phaseB2<<<NB*BLOCKS_PER_B, 256, 0, stream>>>(maps, bits, pos_num, neg_tot, hist1, hist2, v1s, k2s, flb);
    psel_phaseB4<<<NB*BLOCKS_PER_B, 256, 0, stream>>>(maps, bits, hist2, hist3, v1s, k2s, v2s, k3s, flb);
    psel_phaseC <<<NB*BLOCKS_PER_B, 256, 0, stream>>>(maps, gk, bits, hist3, v1s, v2s, k3s, flb, acc);
    psel_phaseD <<<1, 64, 0, stream>>>(acc, out);
}

// Round 3
// 123.445 us; speedup vs baseline: 1.6264x; 1.0019x over previous
//
#include <hip/hip_runtime.h>

#define NB 16
#define NC 7
#define NK 6
#define HC 160
#define WC 160
#define HF 640
#define WF 640
#define NCOARSE (HC*WC)             // 25600 coarse pixels per batch
#define NFINE   (HF*WF)             // 409600 fine pixels per batch
#define BLOCKS_PER_B (NCOARSE/256)  // 100
#define NACC 27
#define ACC_STRIDE 32
#define EPSF 1e-6f

// ---------------- ws layout (bytes) ----------------
// acc      float[16*32]        @ 0          (2048)
// pos_num  int[16]             @ 2048
// neg_tot  int[16]             @ 2112
// v1       int[16]             @ 2176
// k2       int[16]             @ 2240
// v2       int[16]             @ 2304
// k3       int[16]             @ 2368
// fallback int[16]             @ 2432
// hist1    int[16][2048]       @ 4096       (131072)
// hist2    int[16][2048]       @ 135168     (131072)
// hist3    int[16][1024]       @ 266240     (65536)
// bits     uint[16*25600]      @ 331776     (1638400)   [not zeroed]
#define WS_POS   2048
#define WS_NEG   2112
#define WS_V1    2176
#define WS_K2    2240
#define WS_V2    2304
#define WS_K3    2368
#define WS_FLB   2432
#define WS_H1    4096
#define WS_H2    135168
#define WS_H3    266240
#define WS_BITS  331776
#define WS_ZERO_BYTES 331776   // multiple of 16

// ---------- init: zero acc/counters/histograms (replaces pathological hipMemsetAsync) ----------
__global__ __launch_bounds__(256) void psel_init(uint4* __restrict__ ws4) {
    int i = blockIdx.x * 256 + threadIdx.x;
    if (i < WS_ZERO_BYTES / 16) ws4[i] = uint4{0u, 0u, 0u, 0u};
}

__device__ __forceinline__ unsigned score_key(float s) {
    unsigned u = __float_as_uint(s);
    return (u & 0x80000000u) ? ~u : (u | 0x80000000u);
}

// Chunked weighted descending select: find bin v such that cumulative weight
// (from bin NBINS-1 downward) first reaches >= k at v; krem = k - weight strictly above v.
// All 256 threads must call (block-uniform). Result broadcast to all threads.
template<int NBINS>
__device__ __forceinline__ void select_bin(const int* __restrict__ gh, int k, int& bin, int& krem)
{
    constexpr int CH = NBINS / 256;
    __shared__ int lh[NBINS];
    __shared__ int cs[256];
    __shared__ int res[2];
    int t = threadIdx.x;
    #pragma unroll
    for (int i = 0; i < CH; ++i) lh[t + 256*i] = gh[t + 256*i];
    __syncthreads();
    int s = 0;
    #pragma unroll
    for (int j = 0; j < CH; ++j) s += lh[t*CH + j];
    cs[t] = s;
    __syncthreads();
    if (t == 0) {
        int cum = 0, v = 0; bool found = false;
        for (int c = 255; c >= 0 && !found; --c) {
            if (cum + cs[c] >= k) {
                for (int u = c*CH + CH - 1; u >= c*CH; --u) {
                    cum += lh[u];
                    if (cum >= k) { v = u; found = true; break; }
                }
                if (!found) { v = c*CH; found = true; }   // guard (unreachable)
            } else cum += cs[c];
        }
        if (!found) { v = 0; cum = k; }                   // guard (unreachable)
        res[0] = v; res[1] = k - (cum - lh[v]);
    }
    __syncthreads();
    bin = res[0]; krem = res[1];
}

// ---------- Phase A: bit-pack g/m, pos/neg counts, level-1 weighted histogram ----------
__global__ __launch_bounds__(256) void psel_phaseA(
    const float* __restrict__ maps, const float* __restrict__ gt,
    const float* __restrict__ tm, int* __restrict__ pos_num,
    int* __restrict__ neg_tot, int* __restrict__ hist1,
    unsigned* __restrict__ bitsbuf)
{
    __shared__ int lh[2048];
    __shared__ int sp[4], sn[4];
    int t = threadIdx.x;
    #pragma unroll
    for (int i = 0; i < 8; ++i) lh[t + 256*i] = 0;

    int bid = blockIdx.x;
    int b = bid / BLOCKS_PER_B;
    int r = (bid % BLOCKS_PER_B) * 256 + t;
    int cy = r / WC, cx = r % WC;
    const float* gtb = gt + (size_t)b * NFINE;
    const float* tmb = tm + (size_t)b * NFINE;
    unsigned gb = 0, mb = 0;
    #pragma unroll
    for (int row = 0; row < 4; ++row) {
        int off = (cy*4 + row)*WF + cx*4;
        float4 g4 = *reinterpret_cast<const float4*>(gtb + off);
        float4 m4 = *reinterpret_cast<const float4*>(tmb + off);
        unsigned sh = 4*row;
        gb |= ((g4.x > 0.5f) ? 1u : 0u) << (sh+0);
        gb |= ((g4.y > 0.5f) ? 1u : 0u) << (sh+1);
        gb |= ((g4.z > 0.5f) ? 1u : 0u) << (sh+2);
        gb |= ((g4.w > 0.5f) ? 1u : 0u) << (sh+3);
        mb |= ((m4.x > 0.5f) ? 1u : 0u) << (sh+0);
        mb |= ((m4.y > 0.5f) ? 1u : 0u) << (sh+1);
        mb |= ((m4.z > 0.5f) ? 1u : 0u) << (sh+2);
        mb |= ((m4.w > 0.5f) ? 1u : 0u) << (sh+3);
    }
    bitsbuf[b*NCOARSE + r] = (mb << 16) | gb;
    int posc = __popc(gb & mb);
    int negc = 16 - __popc(gb);

    unsigned key = score_key(maps[(size_t)b * NC * NCOARSE + r]);  // channel 0
    __syncthreads();
    if (negc) atomicAdd(&lh[key >> 21], negc);

    // block-reduce pos/neg counts (64-lane wave)
    #pragma unroll
    for (int off = 32; off; off >>= 1) {
        posc += __shfl_down(posc, off);
        negc += __shfl_down(negc, off);
    }
    int wid = t >> 6, lane = t & 63;
    if (lane == 0) { sp[wid] = posc; sn[wid] = negc; }
    __syncthreads();
    if (t == 0) {
        atomicAdd(&pos_num[b], sp[0]+sp[1]+sp[2]+sp[3]);
        atomicAdd(&neg_tot[b], sn[0]+sn[1]+sn[2]+sn[3]);
    }
    // flush level-1 histogram
    int* gh = hist1 + b*2048;
    #pragma unroll
    for (int i = 0; i < 8; ++i) {
        int v = lh[t + 256*i];
        if (v) atomicAdd(&gh[t + 256*i], v);
    }
}

// ---------- Phase B2: scan level-1 (redundant per block) + build level-2 histogram ----------
__global__ __launch_bounds__(256) void psel_phaseB2(
    const float* __restrict__ maps, const unsigned* __restrict__ bitsbuf,
    const int* __restrict__ pos_num, const int* __restrict__ neg_tot,
    const int* __restrict__ hist1, int* __restrict__ hist2,
    int* __restrict__ v1s, int* __restrict__ k2s, int* __restrict__ flb)
{
    int bid = blockIdx.x;
    int b = bid / BLOCKS_PER_B;
    bool desig = (bid % BLOCKS_PER_B) == 0;
    long long pos = pos_num[b];
    long long negT = neg_tot[b];
    long long neg_num = pos * 3; if (neg_num > negT) neg_num = negT;
    if (pos == 0 || neg_num == 0) {
        if (desig && threadIdx.x == 0) flb[b] = 1;
        return;
    }
    int v1, k2;
    select_bin<2048>(hist1 + b*2048, (int)neg_num, v1, k2);
    if (desig && threadIdx.x == 0) { v1s[b] = v1; k2s[b] = k2; }

    int r = (bid % BLOCKS_PER_B) * 256 + threadIdx.x;
    unsigned key = score_key(maps[(size_t)b * NC * NCOARSE + r]);
    if ((int)(key >> 21) == v1) {
        int w = 16 - __popc(bitsbuf[b*NCOARSE + r] & 0xFFFFu);
        if (w) atomicAdd(&hist2[b*2048 + (int)((key >> 10) & 2047u)], w);
    }
}

// ---------- Phase B4: scan level-2 (redundant) + build level-3 histogram ----------
__global__ __launch_bounds__(256) void psel_phaseB4(
    const float* __restrict__ maps, const unsigned* __restrict__ bitsbuf,
    const int* __restrict__ hist2, int* __restrict__ hist3,
    const int* __restrict__ v1s, const int* __restrict__ k2s,
    int* __restrict__ v2s, int* __restrict__ k3s, const int* __restrict__ flb)
{
    int bid = blockIdx.x;
    int b = bid / BLOCKS_PER_B;
    if (flb[b]) return;
    bool desig = (bid % BLOCKS_PER_B) == 0;
    int v1 = v1s[b], k2 = k2s[b];
    int v2, k3;
    select_bin<2048>(hist2 + b*2048, k2, v2, k3);
    if (desig && threadIdx.x == 0) { v2s[b] = v2; k3s[b] = k3; }

    int r = (bid % BLOCKS_PER_B) * 256 + threadIdx.x;
    unsigned key = score_key(maps[(size_t)b * NC * NCOARSE + r]);
    if ((int)(key >> 10) == ((v1 << 11) | v2)) {
        int w = 16 - __popc(bitsbuf[b*NCOARSE + r] & 0xFFFFu);
        if (w) atomicAdd(&hist3[b*1024 + (int)(key & 1023u)], w);
    }
}

// ---------- Phase C: scan level-3 (redundant) + main fused reduction ----------
__global__ __launch_bounds__(256) void psel_phaseC(
    const float* __restrict__ maps, const float* __restrict__ gk,
    const unsigned* __restrict__ bitsbuf, const int* __restrict__ hist3,
    const int* __restrict__ v1s, const int* __restrict__ v2s,
    const int* __restrict__ k3s, const int* __restrict__ flb,
    float* __restrict__ acc)
{
    int bid = blockIdx.x;
    int b = bid / BLOCKS_PER_B;
    int fb = flb[b];
    unsigned thrkey = 0;
    if (!fb) {
        int v3, ku;
        select_bin<1024>(hist3 + b*1024, k3s[b], v3, ku);
        thrkey = ((unsigned)v1s[b] << 21) | ((unsigned)v2s[b] << 10) | (unsigned)v3;
    }

    int r = (bid % BLOCKS_PER_B) * 256 + threadIdx.x;
    int cy = r / WC, cx = r % WC;

    float sig[NC]; float mv0 = 0.f, mv6 = 0.f;
    #pragma unroll
    for (int c = 0; c < NC; ++c) {
        float mv = maps[((size_t)(b*NC + c))*NCOARSE + r];
        if (c == 0) mv0 = mv;
        if (c == 6) mv6 = mv;
        sig[c] = 1.0f / (1.0f + expf(-mv));
    }
    bool at = mv0 > 0.0f;
    bool a5 = mv6 > 0.0f;
    bool cthr = fb || (score_key(mv0) >= thrkey);

    unsigned bits = bitsbuf[b*NCOARSE + r];
    unsigned mbits = bits >> 16, gbits = bits & 0xFFFFu;
    unsigned gmb = mbits & gbits;
    float cm  = (float)__popc(mbits);
    float cgm = (float)__popc(gmb);

    float cgkm[NK] = {0.f,0.f,0.f,0.f,0.f,0.f};
    float cg5mg = 0.f;
    #pragma unroll
    for (int row = 0; row < 4; ++row) {
        int fy = cy*4 + row;
        unsigned mrow = (mbits >> (4*row)) & 15u;
        unsigned grow = (gmb   >> (4*row)) & 15u;
        const float* base = gk + ((size_t)(b*NK)*HF + fy)*WF + cx*4;
        #pragma unroll
        for (int k = 0; k < NK; ++k) {
            float4 k4 = *reinterpret_cast<const float4*>(base + (size_t)k*HF*WF);
            float s = 0.f;
            if (mrow & 1u) s += k4.x;
            if (mrow & 2u) s += k4.y;
            if (mrow & 4u) s += k4.z;
            if (mrow & 8u) s += k4.w;
            cgkm[k] += s;
            if (k == NK-1) {
                float s5 = 0.f;
                if (grow & 1u) s5 += k4.x;
                if (grow & 2u) s5 += k4.y;
                if (grow & 4u) s5 += k4.z;
                if (grow & 8u) s5 += k4.w;
                cg5mg += s5;
            }
        }
    }

    float vals[NACC];
    float s0 = sig[0];
    vals[0] = s0 * cgm;                          // A_t
    vals[1] = s0 * s0 * (cthr ? cm : cgm);       // B_t
    vals[2] = cgm;                               // C_t
    vals[3] = cm;                                // S_cm
    vals[4] = at ? cgm : 0.f;                    // n11 text
    vals[5] = at ? cm  : 0.f;
    #pragma unroll
    for (int k = 0; k < NK; ++k) {
        float sk = sig[k+1];
        vals[6 + 3*k] = at ? sk * cgkm[k] : 0.f;       // A_k
        vals[7 + 3*k] = at ? sk * sk * cm : 0.f;       // B_k
        vals[8 + 3*k] = at ? cgkm[k] : 0.f;            // C_k
    }
    vals[24] = a5 ? cg5mg : 0.f;                 // m11 kernel-iou
    vals[25] = a5 ? cgm   : 0.f;
    vals[26] = cg5mg;

    #pragma unroll
    for (int i = 0; i < NACC; ++i) {
        #pragma unroll
        for (int off = 32; off; off >>= 1)
            vals[i] += __shfl_down(vals[i], off);
    }
    __shared__ float red[4][NACC];
    int wid = threadIdx.x >> 6, lane = threadIdx.x & 63;
    if (lane == 0) {
        #pragma unroll
        for (int i = 0; i < NACC; ++i) red[wid][i] = vals[i];
    }
    __syncthreads();
    if (threadIdx.x < NACC) {
        float s = red[0][threadIdx.x] + red[1][threadIdx.x]
                + red[2][threadIdx.x] + red[3][threadIdx.x];
        atomicAdd(&acc[b*ACC_STRIDE + threadIdx.x], s);
    }
}

// ---------- Phase D: final per-batch algebra + output sums ----------
__global__ __launch_bounds__(64) void psel_phaseD(
    const float* __restrict__ acc, float* __restrict__ out)
{
    int b = threadIdx.x;
    float l = 0.f, lt = 0.f, lk = 0.f, it = 0.f, ik = 0.f;
    if (b < NB) {
        const float* a = acc + b*ACC_STRIDE;
        float At = a[0], Bt = a[1], Ct = a[2], Sm = a[3], Satgm = a[4], Satm = a[5];
        lt = 1.f - 2.f*At / (Bt + Ct + 2.f*EPSF);
        float n11 = Satgm;
        float u1 = Satm + Ct - Satgm;
        float i0 = Sm - u1;
        float u0 = Sm - n11;
        it = 0.5f * (i0/(u0 + EPSF) + n11/(u1 + EPSF));
        float lks = 0.f;
        #pragma unroll
        for (int k = 0; k < NK; ++k) {
            float Ak = a[6+3*k], Bk = a[7+3*k], Ck = a[8+3*k];
            lks += 1.f - 2.f*Ak / (Bk + Ck + 2.f*EPSF);
        }
        lk = lks / (float)NK;
        float m11 = a[24], Sa5gm = a[25], Sg5 = a[26];
        float ku1 = Sa5gm + Sg5 - m11;
        float ki0 = Ct - ku1;
        float ku0 = Ct - m11;
        ik = 0.5f * (ki0/(ku0 + EPSF) + m11/(ku1 + EPSF));
        l = 0.7f*lt + 0.3f*lk;
    }
    #pragma unroll
    for (int off = 8; off; off >>= 1) {
        l  += __shfl_down(l,  off);
        lt += __shfl_down(lt, off);
        lk += __shfl_down(lk, off);
        it += __shfl_down(it, off);
        ik += __shfl_down(ik, off);
    }
    if (threadIdx.x == 0) {
        out[0] = l; out[1] = lt; out[2] = lk; out[3] = it; out[4] = ik;
    }
}

extern "C" void kernel_launch(void* const* d_in, const int* in_sizes, int n_in,
                              void* d_out, int out_size, void* d_ws, size_t ws_size,
                              hipStream_t stream) {
    const float* maps = (const float*)d_in[0];
    const float* gt   = (const float*)d_in[1];
    const float* gk   = (const float*)d_in[2];
    const float* tm   = (const float*)d_in[3];
    float* out = (float*)d_out;
    char* ws = (char*)d_ws;
    float* acc      = (float*)ws;
    int*   pos_num  = (int*)(ws + WS_POS);
    int*   neg_tot  = (int*)(ws + WS_NEG);
    int*   v1s      = (int*)(ws + WS_V1);
    int*   k2s      = (int*)(ws + WS_K2);
    int*   v2s      = (int*)(ws + WS_V2);
    int*   k3s      = (int*)(ws + WS_K3);
    int*   flb      = (int*)(ws + WS_FLB);
    int*   hist1    = (int*)(ws + WS_H1);
    int*   hist2    = (int*)(ws + WS_H2);
    int*   hist3    = (int*)(ws + WS_H3);
    unsigned* bits  = (unsigned*)(ws + WS_BITS);

    psel_init   <<<(WS_ZERO_BYTES/16 + 255)/256, 256, 0, stream>>>((uint4*)ws);
    psel_phaseA <<<NB*BLOCKS_PER_B, 256, 0, stream>>>(maps, gt, tm, pos_num, neg_tot, hist1, bits);
    psel_phaseB2<<<NB*BLOCKS_PER_B, 256, 0, stream>>>(maps, bits, pos_num, neg_tot, hist1, hist2, v1s, k2s, flb);
    psel_phaseB4<<<NB*BLOCKS_PER_B, 256, 0, stream>>>(maps, bits, hist2, hist3, v1s, k2s, v2s, k3s, flb);
    psel_phaseC <<<NB*BLOCKS_PER_B, 256, 0, stream>>>(maps, gk, bits, hist3, v1s, v2s, k3s, flb, acc);
    psel_phaseD <<<1, 64, 0, stream>>>(acc, out);
}